// Round 15
// baseline (324.554 us; speedup 1.0000x reference)
//
#include <hip/hip_runtime.h>
#include <math.h>

#define NROWS 64
#define DCOLS 512
#define WPB   4              // waves (=batches) per block
#define BDIM  (WPB * 64)

typedef float f32x4 __attribute__((ext_vector_type(4)));

__device__ __forceinline__ void wave_reduce_sum2(float& a, float& b) {
#pragma unroll
    for (int off = 32; off > 0; off >>= 1) {
        a += __shfl_xor(a, off, 64);
        b += __shfl_xor(b, off, 64);
    }
}
__device__ __forceinline__ float wave_reduce_sum(float v) {
#pragma unroll
    for (int off = 32; off > 0; off >>= 1)
        v += __shfl_xor(v, off, 64);
    return v;
}

__device__ __forceinline__ float hsum8(f32x4 a, f32x4 b) {
    return ((a.x + a.y) + (a.z + a.w)) + ((b.x + b.y) + (b.z + b.w));
}
__device__ __forceinline__ float hsumsq8(f32x4 a, f32x4 b) {
    return (a.x*a.x + a.y*a.y + a.z*a.z + a.w*a.w)
         + (b.x*b.x + b.y*b.y + b.z*b.z + b.w*b.w);
}

// tanh(x) = 1 - 2/(exp(2x)+1); correct both signs, saturates at +/-1.
__device__ __forceinline__ float fast_tanh(float x) {
    float e = __expf(2.0f * x);
    return 1.0f - 2.0f / (e + 1.0f);
}

// One wave per batch element: no __syncthreads, no LDS, no inter-wave
// dependency of any kind. 64 rows <-> 64 lanes for stat parking.
__global__ __launch_bounds__(BDIM, 4) void fused_ln_attn_kernel(
    const float* __restrict__ emb,
    const float* __restrict__ gamma,
    const float* __restrict__ beta,
    const float* __restrict__ Wv,
    const float* __restrict__ bv,
    float* __restrict__ out)
{
    const int lane  = threadIdx.x & 63;
    const int wv    = threadIdx.x >> 6;
    const int batch = blockIdx.x * WPB + wv;
    const int c0    = lane << 2;        // cols [4l, 4l+4)
    const int c1    = 256 + c0;         // cols [256+4l, ...)

    const float* eb = emb + (size_t)batch * (NROWS * DCOLS);
    float*       ob = out + (size_t)batch * (NROWS * DCOLS);

    // per-column params (L1-hot broadcast loads, reused 64x per wave)
    const f32x4 g0 = *(const f32x4*)(gamma + c0);
    const f32x4 g1 = *(const f32x4*)(gamma + c1);
    const f32x4 b0 = *(const f32x4*)(beta + c0);
    const f32x4 b1 = *(const f32x4*)(beta + c1);
    const f32x4 w0 = *(const f32x4*)(Wv + c0);
    const f32x4 w1 = *(const f32x4*)(Wv + c1);
    const float bias = bv[0];

    // ---- row 0: the query ----
    f32x4 q0, q1;
    {
        const f32x4 x0 = *(const f32x4*)(eb + c0);
        const f32x4 x1 = *(const f32x4*)(eb + c1);
        float s = hsum8(x0, x1), ss = hsumsq8(x0, x1);
        wave_reduce_sum2(s, ss);
        const float mu  = s * (1.0f / (float)DCOLS);
        const float var = ss * (1.0f / (float)DCOLS) - mu * mu;
        const float rs  = rsqrtf(var + 1e-5f);
        q0 = (x0 - mu) * rs * g0 + b0;
        q1 = (x1 - mu) * rs * g1 + b1;
        __builtin_nontemporal_store(q0, (f32x4*)(ob + c0));
        __builtin_nontemporal_store(q1, (f32x4*)(ob + c1));
    }

    // lane r parks row r's stats (lane 0 keeps exS=0: row 0 not in softmax)
    float muS = 0.0f, rsS = 0.0f, exS = 0.0f;

    // ---- Pass A: rows 1..63 — LN stats + score, depth-1 pipelined ----
    f32x4 xa = *(const f32x4*)(eb + DCOLS + c0);
    f32x4 xb = *(const f32x4*)(eb + DCOLS + c1);
#pragma unroll 1
    for (int r = 1; r < NROWS; ++r) {
        const f32x4 y0 = xa, y1 = xb;
        if (r + 1 < NROWS) {
            xa = *(const f32x4*)(eb + (r + 1) * DCOLS + c0);
            xb = *(const f32x4*)(eb + (r + 1) * DCOLS + c1);
        }
        float s = hsum8(y0, y1), ss = hsumsq8(y0, y1);
        wave_reduce_sum2(s, ss);
        const float mu  = s * (1.0f / (float)DCOLS);
        const float var = ss * (1.0f / (float)DCOLS) - mu * mu;
        const float rs  = rsqrtf(var + 1e-5f);

        const f32x4 e0 = (y0 - mu) * rs * g0 + b0;
        const f32x4 e1 = (y1 - mu) * rs * g1 + b1;

        float p;
        p  = fast_tanh(q0.x * e0.x) * w0.x;
        p += fast_tanh(q0.y * e0.y) * w0.y;
        p += fast_tanh(q0.z * e0.z) * w0.z;
        p += fast_tanh(q0.w * e0.w) * w0.w;
        p += fast_tanh(q1.x * e1.x) * w1.x;
        p += fast_tanh(q1.y * e1.y) * w1.y;
        p += fast_tanh(q1.z * e1.z) * w1.z;
        p += fast_tanh(q1.w * e1.w) * w1.w;

        const float tot = wave_reduce_sum(p) + bias;
        const float ex  = __expf(tot);   // max-free: |tot| <= sum|Wv| + |bv| ~ 18

        if (lane == r) { muS = mu; rsS = rs; exS = ex; }
    }

    const float inv = 1.0f / wave_reduce_sum(exS);

    // ---- Pass C: rows 1..63 — re-read x (L3-hot, ~1.5us window),
    //      recompute e from parked stats, scale, store ----
    xa = *(const f32x4*)(eb + DCOLS + c0);
    xb = *(const f32x4*)(eb + DCOLS + c1);
#pragma unroll 1
    for (int r = 1; r < NROWS; ++r) {
        const f32x4 y0 = xa, y1 = xb;
        if (r + 1 < NROWS) {
            xa = *(const f32x4*)(eb + (r + 1) * DCOLS + c0);
            xb = *(const f32x4*)(eb + (r + 1) * DCOLS + c1);
        }
        const float mu = __shfl(muS, r, 64);
        const float rs = __shfl(rsS, r, 64);
        const float a  = __shfl(exS, r, 64) * inv;

        const f32x4 o0 = ((y0 - mu) * rs * g0 + b0) * a;
        const f32x4 o1 = ((y1 - mu) * rs * g1 + b1) * a;
        __builtin_nontemporal_store(o0, (f32x4*)(ob + r * DCOLS + c0));
        __builtin_nontemporal_store(o1, (f32x4*)(ob + r * DCOLS + c1));
    }
}

extern "C" void kernel_launch(void* const* d_in, const int* in_sizes, int n_in,
                              void* d_out, int out_size, void* d_ws, size_t ws_size,
                              hipStream_t stream) {
    const float* emb   = (const float*)d_in[0];
    const float* gamma = (const float*)d_in[1];
    const float* beta  = (const float*)d_in[2];
    const float* Wv    = (const float*)d_in[3];
    const float* bv    = (const float*)d_in[4];
    float* out = (float*)d_out;

    const int B = in_sizes[0] / (NROWS * DCOLS);
    const int grid = B / WPB;
    fused_ln_attn_kernel<<<grid, BDIM, 0, stream>>>(emb, gamma, beta, Wv, bv, out);
}

// Round 16
// 217.877 us; speedup vs baseline: 1.4896x; 1.4896x over previous
//
#include <hip/hip_runtime.h>
#include <math.h>

#define NROWS 64
#define DCOLS 512
#define HCOL  256
#define BDIM  512
#define NWV   8     // waves per block
#define RPW   8     // rows per wave: 64 rows / 8 waves
#define BPB   8     // batches per block: grid = 4096/8 = 512 = 2 blocks/CU

typedef float f32x4 __attribute__((ext_vector_type(4)));

__device__ __forceinline__ void wave_reduce_sum2(float& a, float& b) {
#pragma unroll
    for (int off = 32; off > 0; off >>= 1) {
        a += __shfl_xor(a, off, 64);
        b += __shfl_xor(b, off, 64);
    }
}
__device__ __forceinline__ float wave_reduce_sum(float v) {
#pragma unroll
    for (int off = 32; off > 0; off >>= 1)
        v += __shfl_xor(v, off, 64);
    return v;
}

__device__ __forceinline__ float hsum8(f32x4 a, f32x4 b) {
    return ((a.x + a.y) + (a.z + a.w)) + ((b.x + b.y) + (b.z + b.w));
}
__device__ __forceinline__ float hsumsq8(f32x4 a, f32x4 b) {
    return (a.x*a.x + a.y*a.y + a.z*a.z + a.w*a.w)
         + (b.x*b.x + b.y*b.y + b.z*b.z + b.w*b.w);
}

// tanh(x) = 1 - 2/(exp(2x)+1); correct both signs, saturates at +/-1.
__device__ __forceinline__ float fast_tanh(float x) {
    float e = __expf(2.0f * x);
    return 1.0f - 2.0f / (e + 1.0f);
}

// LDS-ordering barrier: does NOT drain vmcnt (loads / nt-stores / DMAs stay
// in flight across it).
__device__ __forceinline__ void lds_barrier() {
    asm volatile("s_waitcnt lgkmcnt(0)" ::: "memory");
    __builtin_amdgcn_s_barrier();
}

// async global->LDS: 16B/lane, LDS dest = uniform base + lane*16. Lane l owns
// cols [4l,4l+4) of a 256-wide half-row -> exact match, 1 KiB per instr.
__device__ __forceinline__ void glds16(const float* g, float* l) {
    __builtin_amdgcn_global_load_lds(
        (const __attribute__((address_space(1))) void*)g,
        (__attribute__((address_space(3)))       void*)l,
        16, 0, 0);
}

__global__ __launch_bounds__(BDIM, 4) void fused_ln_attn_kernel(
    const float* __restrict__ emb,
    const float* __restrict__ gamma,
    const float* __restrict__ beta,
    const float* __restrict__ Wv,
    const float* __restrict__ bv,
    float* __restrict__ out,
    int B)
{
    // ~72.2 KiB -> 2 blocks/CU (R10-verified occupancy governor: RA gets the
    // 128-VGPR tier, no spill-for-occupancy).
    __shared__ __align__(16) float s_buf[NROWS * HCOL];  // x1 staged -> e1 in place
    __shared__ __align__(16) float s_q[DCOLS];
    __shared__ __align__(16) float s_g[DCOLS];
    __shared__ __align__(16) float s_b[DCOLS];
    __shared__ __align__(16) float s_w[DCOLS];
    __shared__ float s_den[2][NWV];

    const int tid  = threadIdx.x;
    const int wave = tid >> 6;
    const int lane = tid & 63;
    const int c0   = lane << 2;
    const int c1   = HCOL + c0;
    const int r0   = wave * RPW;

    s_g[tid] = gamma[tid];
    s_b[tid] = beta[tid];
    s_w[tid] = Wv[tid];
    const float bias = bv[0];

    const int bstart = blockIdx.x * BPB;

    // ---- prologue: stage x1(0) via DMA, prefetch cx0(0) into regs ----
    f32x4 cx0[RPW];
    {
        const float* eb = emb + (size_t)bstart * (NROWS * DCOLS);
#pragma unroll
        for (int i = 0; i < RPW; ++i) {
            const int r = r0 + i;
            glds16(eb + r * DCOLS + c1, s_buf + r * HCOL);
            cx0[i] = *(const f32x4*)(eb + r * DCOLS + c0);
        }
    }
    // one-time full drain (prologue order is mixed; not countable)
    asm volatile("s_waitcnt vmcnt(0) lgkmcnt(0)" ::: "memory");
    __builtin_amdgcn_s_barrier();   // params + staged x1(0) visible

#pragma unroll 1
    for (int t = 0; t < BPB; ++t) {
        const int bb = bstart + t;
        const float* eb = emb + (size_t)bb * (NROWS * DCOLS);
        float*       ob = out + (size_t)bb * (NROWS * DCOLS);

        // Counted per-wave wait: the 8 newest VM ops are last iter's c0-half
        // stores (left in flight); everything older -- restage DMAs, c1
        // stores, cx0 prefetch -- has landed. No full store drain. t=0: no-op.
        asm volatile("s_waitcnt vmcnt(8)" ::: "memory");
        __builtin_amdgcn_sched_barrier(0);

        // ---- Pass 1: LN; e0 -> regs, e1 overwrites its x1 slot in LDS ----
        f32x4 e0[RPW];
        {
            const f32x4 g0 = *(const f32x4*)(s_g + c0);
            const f32x4 g1 = *(const f32x4*)(s_g + c1);
            const f32x4 b0 = *(const f32x4*)(s_b + c0);
            const f32x4 b1 = *(const f32x4*)(s_b + c1);
#pragma unroll
            for (int i = 0; i < RPW; ++i) {
                const int r = r0 + i;
                const f32x4 x0 = cx0[i];
                const f32x4 x1 = *(const f32x4*)(s_buf + r * HCOL + c0);

                float s = hsum8(x0, x1), ss = hsumsq8(x0, x1);
                wave_reduce_sum2(s, ss);

                const float mu  = s * (1.0f / (float)DCOLS);
                const float var = ss * (1.0f / (float)DCOLS) - mu * mu;
                const float rs  = rsqrtf(var + 1e-5f);

                e0[i] = (x0 - mu) * rs * g0 + b0;
                const f32x4 t1 = (x1 - mu) * rs * g1 + b1;
                *(f32x4*)(s_buf + r * HCOL + c0) = t1;   // own slot, in place

                if (wave == 0 && i == 0) {   // publish q (store via uniform path)
                    *(f32x4*)(s_q + c0) = e0[0];
                    *(f32x4*)(s_q + c1) = t1;
                }
            }
        }

        // ---- prefetch next batch's cx0 (oldest VM group of this iter) ----
        if (t + 1 < BPB) {
            const float* nb = eb + NROWS * DCOLS;
#pragma unroll
            for (int i = 0; i < RPW; ++i)
                cx0[i] = *(const f32x4*)(nb + (r0 + i) * DCOLS + c0);
        }
        __builtin_amdgcn_sched_barrier(0);

        lds_barrier();   // barrier 1: q + e1 visible

        const f32x4 q0 = *(const f32x4*)(s_q + c0);
        const f32x4 q1 = *(const f32x4*)(s_q + c1);
        const f32x4 w0 = *(const f32x4*)(s_w + c0);
        const f32x4 w1 = *(const f32x4*)(s_w + c1);

        // ---- Pass 2: scores + per-wave softmax partials (max-free:
        //      |score| <= sum|Wv_d| + |bv| ~ 18, f32 exp is safe) ----
        float ex[RPW];
        float denw = 0.0f;
#pragma unroll
        for (int i = 0; i < RPW; ++i) {
            const int r = r0 + i;
            const f32x4 t1 = *(const f32x4*)(s_buf + r * HCOL + c0);
            float p;
            p  = fast_tanh(q0.x * e0[i].x) * w0.x;
            p += fast_tanh(q0.y * e0[i].y) * w0.y;
            p += fast_tanh(q0.z * e0[i].z) * w0.z;
            p += fast_tanh(q0.w * e0[i].w) * w0.w;
            p += fast_tanh(q1.x * t1.x) * w1.x;
            p += fast_tanh(q1.y * t1.y) * w1.y;
            p += fast_tanh(q1.z * t1.z) * w1.z;
            p += fast_tanh(q1.w * t1.w) * w1.w;
            const float tot = wave_reduce_sum(p) + bias;
            const float e   = __expf(tot);
            ex[i] = (r == 0) ? 0.0f : e;
            denw += ex[i];
        }
        if (lane == 0) s_den[t & 1][wave] = denw;

        lds_barrier();   // barrier 2: partial denominators visible

        float den = 0.0f;
#pragma unroll
        for (int w = 0; w < NWV; ++w) den += s_den[t & 1][w];
        const float inv = 1.0f / den;

        // ---- Pass 3a: c1-half -- read slot, scale, store (frees slot).
        //      Row 0 through the uniform path with a=1 (it's q). ----
#pragma unroll
        for (int i = 0; i < RPW; ++i) {
            const int r = r0 + i;
            const float a  = (r == 0) ? 1.0f : ex[i] * inv;
            const f32x4 t1 = *(const f32x4*)(s_buf + r * HCOL + c0);
            __builtin_nontemporal_store(t1 * a, (f32x4*)(ob + r * DCOLS + c1));
        }
        asm volatile("s_waitcnt lgkmcnt(0)" ::: "memory");   // slot reads done
        __builtin_amdgcn_sched_barrier(0);

        // ---- Pass 3b: restage next batch's x1 into the freed slots ----
        if (t + 1 < BPB) {
            const float* nb = eb + NROWS * DCOLS;
#pragma unroll
            for (int i = 0; i < RPW; ++i)
                glds16(nb + (r0 + i) * DCOLS + c1, s_buf + (r0 + i) * HCOL);
        }
        __builtin_amdgcn_sched_barrier(0);

        // ---- Pass 3c: c0-half stores LAST (the 8 newest VM ops) ----
#pragma unroll
        for (int i = 0; i < RPW; ++i) {
            const int r = r0 + i;
            const float a = (r == 0) ? 1.0f : ex[i] * inv;
            __builtin_nontemporal_store(e0[i] * a, (f32x4*)(ob + r * DCOLS + c0));
        }
    }
}

extern "C" void kernel_launch(void* const* d_in, const int* in_sizes, int n_in,
                              void* d_out, int out_size, void* d_ws, size_t ws_size,
                              hipStream_t stream) {
    const float* emb   = (const float*)d_in[0];
    const float* gamma = (const float*)d_in[1];
    const float* beta  = (const float*)d_in[2];
    const float* Wv    = (const float*)d_in[3];
    const float* bv    = (const float*)d_in[4];
    float* out = (float*)d_out;

    const int B = in_sizes[0] / (NROWS * DCOLS);
    const int grid = (B + BPB - 1) / BPB;
    fused_ln_attn_kernel<<<grid, BDIM, 0, stream>>>(emb, gamma, beta, Wv, bv, out, B);
}